// Round 19
// baseline (135.490 us; speedup 1.0000x reference)
//
#include <hip/hip_runtime.h>

#define NB 8
#define N1 8192
#define N2 2048
#define C1 256
#define C2 512
#define CO 768   // C1 + C2
#define CCH 4    // channels per interp block

typedef float f2 __attribute__((ext_vector_type(2)));
typedef float f4 __attribute__((ext_vector_type(4)));

// ws: keys4 (B*N2 float4 = 256 KB) | nn_idx (B*N1*4 ints = 1 MB) |
//     nn_w (B*N1*4 floats = 1 MB). Total 2.25 MB.  (R11..R18-exact layout)

// ---------------------------------------------------------------------------
// ASM-PINNED arithmetic — VERBATIM R14..R18 (validated, absmax 0.015625).
// ---------------------------------------------------------------------------
#define NRM2(X, Y, Z) ({                                                   \
    float _s, _t;                                                          \
    asm("v_mul_f32 %0, %2, %2\n\t"                                         \
        "v_mul_f32 %1, %3, %3\n\t"                                         \
        "v_add_f32 %0, %0, %1\n\t"                                         \
        "v_mul_f32 %1, %4, %4\n\t"                                         \
        "v_add_f32 %0, %0, %1"                                             \
        : "=&v"(_s), "=&v"(_t) : "v"(X), "v"(Y), "v"(Z));                  \
    _s; })

#define PKD2(X01, Y01, Z01, K01, QXD, QYD, QZD, QQD, M2) ({                \
    f2 _d, _s;                                                             \
    asm("v_pk_mul_f32 %0, %2, %6\n\t"      /* kx*qx per half        */     \
        "v_pk_fma_f32 %0, %3, %7, %0\n\t"  /* + ky*qy               */     \
        "v_pk_fma_f32 %0, %4, %8, %0\n\t"  /* + kz*qz -> dot        */     \
        "v_pk_add_f32 %1, %5, %9\n\t"      /* kk+qq                 */     \
        "v_pk_fma_f32 %0, %0, %10, %1"     /* d2 = dot*(-2)+(kk+qq) */     \
        : "=&v"(_d), "=&v"(_s)                                             \
        : "v"(X01), "v"(Y01), "v"(Z01), "v"(K01),                          \
          "v"(QXD), "v"(QYD), "v"(QZD), "v"(QQD), "v"(M2));                \
    _d; })

// Branchy top-3 insert — VERBATIM R14..R18 (validated).
#define INS(S, D2, J) do {                                                 \
        float _v = (D2);                                                   \
        if (_v < b2##S) {                                                  \
            bool c0 = _v < b0##S, c1 = _v < b1##S;                         \
            b2##S = c1 ? b1##S : _v;                                       \
            i2##S = c1 ? i1##S : (J);                                      \
            b1##S = c0 ? b0##S : (c1 ? _v : b1##S);                        \
            i1##S = c0 ? i0##S : (c1 ? (J) : i1##S);                       \
            b0##S = c0 ? _v : b0##S;                                       \
            i0##S = c0 ? (J) : i0##S;                                      \
        } } while (0)

// ---------------------------------------------------------------------------
// Pack keys to float4(x,y,z,|k|^2) — VERBATIM R18.
// ---------------------------------------------------------------------------
__global__ __launch_bounds__(256) void pack_keys(
    const float* __restrict__ kxyz,   // (B, 3, N2)
    float4* __restrict__ keys4)       // (B, N2)
{
    const int b = blockIdx.x >> 3;
    const int j = (blockIdx.x & 7) * 256 + threadIdx.x;
    const float* kb = kxyz + (size_t)b * 3 * N2;
    float x = kb[j], y = kb[N2 + j], z = kb[2 * N2 + j];
    keys4[(size_t)b * N2 + j] = make_float4(x, y, z, NRM2(x, y, z));
}

// ---------------------------------------------------------------------------
// KNN — Q4 scan (the single change vs R18). Block = 512 thr = 8 waves =
// 256 queries, FOUR per lane (nA..nD = n0+{0,64,128,192}+lane): each
// wave-uniform key-quad broadcast (b128) now serves 4 queries -> per-CU LDS
// broadcast reads halve vs Q2 (R16-measured ~20us LDS wall in the scan).
// Per-key arithmetic (pinned PKD2), insert (INS), chunk partition (8 x 256
// ascending), merge order (chunk asc, rank asc, strict-<), weight math,
// packed stores, folded copy: all byte-equivalent semantics to R18 --
// only the lane<->query-state assignment changes. == jax.lax.top_k.
// ---------------------------------------------------------------------------
__global__ __launch_bounds__(512, 2) void knn_scan(
    const float* __restrict__ qxyz,   // (B, 3, N1)
    const float4* __restrict__ keys4, // (B, N2) packed
    const float* __restrict__ qfeat,  // (B, C1, N1)
    int*   __restrict__ nn_idx,       // (B*N1*4) packed
    float* __restrict__ nn_w,         // (B*N1*4) packed
    float* __restrict__ out)          // (B, CO, N1)
{
    __shared__ __align__(16) float skx[N2];
    __shared__ __align__(16) float sky[N2];
    __shared__ __align__(16) float skz[N2];
    __shared__ __align__(16) float skk[N2];
    __shared__ float pd[8][256][3];    // 24 KB
    __shared__ int   pi[8][256][3];    // 24 KB

    const int b    = blockIdx.x >> 5;       // 32 tiles of 256 queries
    const int tile = blockIdx.x & 31;
    const int n0   = tile * 256;
    const int tid  = threadIdx.x;
    const int w    = tid >> 6, lane = tid & 63;

    // stage keys (coalesced float4 from packed ws; values bit-identical)
    const float4* kb4 = keys4 + (size_t)b * N2;
    for (int j = tid; j < N2; j += 512) {
        float4 k4 = kb4[j];
        skx[j] = k4.x; sky[j] = k4.y; skz[j] = k4.z; skk[j] = k4.w;
    }
    __syncthreads();

    // four queries per lane
    const int nA = n0 + lane, nB = n0 + 64 + lane,
              nC = n0 + 128 + lane, nD = n0 + 192 + lane;
    const float* qb = qxyz + (size_t)b * 3 * N1;
    const float qxA = qb[nA], qyA = qb[N1 + nA], qzA = qb[2 * N1 + nA];
    const float qxB = qb[nB], qyB = qb[N1 + nB], qzB = qb[2 * N1 + nB];
    const float qxC = qb[nC], qyC = qb[N1 + nC], qzC = qb[2 * N1 + nC];
    const float qxD = qb[nD], qyD = qb[N1 + nD], qzD = qb[2 * N1 + nD];
    const float qqA = NRM2(qxA, qyA, qzA);
    const float qqB = NRM2(qxB, qyB, qzB);
    const float qqC = NRM2(qxC, qyC, qzC);
    const float qqD = NRM2(qxD, qyD, qzD);

    f2 m2; m2.x = -2.0f; m2.y = -2.0f;
#define DUP(S) \
    f2 qxd##S, qyd##S, qzd##S, qqd##S; \
    qxd##S.x = qx##S; qxd##S.y = qx##S; qyd##S.x = qy##S; qyd##S.y = qy##S; \
    qzd##S.x = qz##S; qzd##S.y = qz##S; qqd##S.x = qq##S; qqd##S.y = qq##S;
    DUP(A) DUP(B) DUP(C) DUP(D)
#undef DUP

    float b0A = 3.4e38f, b1A = 3.4e38f, b2A = 3.4e38f;
    float b0B = 3.4e38f, b1B = 3.4e38f, b2B = 3.4e38f;
    float b0C = 3.4e38f, b1C = 3.4e38f, b2C = 3.4e38f;
    float b0D = 3.4e38f, b1D = 3.4e38f, b2D = 3.4e38f;
    int   i0A = 0, i1A = 0, i2A = 0, i0B = 0, i1B = 0, i2B = 0;
    int   i0C = 0, i1C = 0, i2C = 0, i0D = 0, i1D = 0, i2D = 0;

    const int jlo = w * (N2 / 8);            // 256 keys per wave-chunk
    #pragma unroll 2
    for (int g = 0; g < (N2 / 8) / 4; ++g) {
        const int jb = jlo + g * 4;
        f4 x4 = *(const f4*)&skx[jb];        // wave-uniform b128 broadcast
        f4 y4 = *(const f4*)&sky[jb];
        f4 z4 = *(const f4*)&skz[jb];
        f4 k4 = *(const f4*)&skk[jb];
#define SCAN(S) do {                                                        \
        f2 d01 = PKD2(x4.xy, y4.xy, z4.xy, k4.xy,                           \
                      qxd##S, qyd##S, qzd##S, qqd##S, m2);                  \
        f2 d23 = PKD2(x4.zw, y4.zw, z4.zw, k4.zw,                           \
                      qxd##S, qyd##S, qzd##S, qqd##S, m2);                  \
        INS(S, d01.x, jb);     INS(S, d01.y, jb + 1);                       \
        INS(S, d23.x, jb + 2); INS(S, d23.y, jb + 3);                       \
    } while (0)
        SCAN(A); SCAN(B); SCAN(C); SCAN(D);
#undef SCAN
    }

#define STORE_STATE(S, QI) do {                                            \
        pd[w][(QI) * 64 + lane][0] = b0##S;                                \
        pd[w][(QI) * 64 + lane][1] = b1##S;                                \
        pd[w][(QI) * 64 + lane][2] = b2##S;                                \
        pi[w][(QI) * 64 + lane][0] = i0##S;                                \
        pi[w][(QI) * 64 + lane][1] = i1##S;                                \
        pi[w][(QI) * 64 + lane][2] = i2##S;                                \
    } while (0)
    STORE_STATE(A, 0); STORE_STATE(B, 1); STORE_STATE(C, 2); STORE_STATE(D, 3);
#undef STORE_STATE
    __syncthreads();

    if (tid < 256) {
        float m0 = 3.4e38f, m1 = 3.4e38f, m2s = 3.4e38f;
        int   j0 = 0, j1 = 0, j2 = 0;
        #pragma unroll
        for (int c = 0; c < 8; ++c) {
            #pragma unroll
            for (int s = 0; s < 3; ++s) {
                float d = pd[c][tid][s];
                int   i = pi[c][tid][s];
                if (d < m2s) {
                    bool c0 = d < m0, c1 = d < m1;
                    m2s = c1 ? m1 : d;               j2 = c1 ? j1 : i;
                    m1 = c0 ? m0 : (c1 ? d : m1);    j1 = c0 ? j0 : (c1 ? i : j1);
                    m0 = c0 ? d : m0;                j0 = c0 ? i  : j0;
                }
            }
        }
        // weights: mirror reference op order (R8-validated, packed store)
        float d0f = fmaxf(m0, 1e-10f), d1f = fmaxf(m1, 1e-10f), d2f = fmaxf(m2s, 1e-10f);
        float v0 = __fdiv_rn(1.0f, d0f), v1 = __fdiv_rn(1.0f, d1f), v2 = __fdiv_rn(1.0f, d2f);
        float s  = __fadd_rn(__fadd_rn(v0, v1), v2);
        const size_t g = (size_t)b * N1 + n0 + tid;
        *(int4*)  &nn_idx[g * 4] = make_int4(j0, j1, j2, 0);
        *(float4*)&nn_w  [g * 4] = make_float4(__fdiv_rn(v0, s), __fdiv_rn(v1, s),
                                               __fdiv_rn(v2, s), 0.0f);
    }

    // Folded qfeat copy (validated float4 stream; rides knn's idle HBM).
    // 256 blocks; per batch: 524288 float4s / 32 tiles = 16384 per block.
    const float4* qsrc = (const float4*)(qfeat + (size_t)b * C1 * N1);
    float4*       qdst = (float4*)(out + (size_t)b * CO * N1 + (size_t)C2 * N1);
    #pragma unroll
    for (int k = 0; k < 32; ++k) {
        const size_t r = (size_t)tile * 16384 + (size_t)k * 512 + tid;
        qdst[r] = qsrc[r];
    }
}

// ---------------------------------------------------------------------------
// Interp v8 — VERBATIM R18 (validated; channel-pair b64 LDS gathers).
// ---------------------------------------------------------------------------
__global__ __launch_bounds__(256) void interp8(
    const float* __restrict__ kfeat,  // (B, C2, N2)
    const int*   __restrict__ nn_idx, // packed stride-4
    const float* __restrict__ nn_w,   // packed stride-4
    float* __restrict__ out)          // (B, CO, N1)
{
    __shared__ __align__(8) f2 skp01[N2];   // 16 KB: channels (c0,c1) per key
    __shared__ __align__(8) f2 skp23[N2];   // 16 KB: channels (c2,c3) per key
    const int b     = blockIdx.x & 7;       // XCD-pinned batch
    const int cg    = blockIdx.x >> 3;      // 0..127
    const int cbase = cg * CCH;
    const int tid   = threadIdx.x;

    const float* kf = kfeat + (size_t)b * C2 * N2 + (size_t)cbase * N2;
    for (int j = tid; j < N2; j += 256) {
        f2 p01, p23;
        p01.x = kf[j];          p01.y = kf[N2 + j];
        p23.x = kf[2 * N2 + j]; p23.y = kf[3 * N2 + j];
        skp01[j] = p01;
        skp23[j] = p23;
    }
    __syncthreads();

    const int*   ib = nn_idx + (size_t)b * N1 * 4;
    const float* wb = nn_w   + (size_t)b * N1 * 4;
    float* ob = out + (size_t)b * CO * N1;

    #pragma unroll 4
    for (int t = 0; t < N1 / 256; ++t) {
        const int n = t * 256 + tid;
        const int4   iv = *(const int4*)  &ib[(size_t)n * 4];
        const float4 wv = *(const float4*)&wb[(size_t)n * 4];
        const f2 a01 = skp01[iv.x], a23 = skp23[iv.x];
        const f2 b01 = skp01[iv.y], b23 = skp23[iv.y];
        const f2 c01 = skp01[iv.z], c23 = skp23[iv.z];
        // per-channel: fmaf(w2,f2, fmaf(w1,f1, mul(w0,f0))) — validated order
        ob[(size_t)(cbase + 0) * N1 + n] =
            fmaf(wv.z, c01.x, fmaf(wv.y, b01.x, __fmul_rn(wv.x, a01.x)));
        ob[(size_t)(cbase + 1) * N1 + n] =
            fmaf(wv.z, c01.y, fmaf(wv.y, b01.y, __fmul_rn(wv.x, a01.y)));
        ob[(size_t)(cbase + 2) * N1 + n] =
            fmaf(wv.z, c23.x, fmaf(wv.y, b23.x, __fmul_rn(wv.x, a23.x)));
        ob[(size_t)(cbase + 3) * N1 + n] =
            fmaf(wv.z, c23.y, fmaf(wv.y, b23.y, __fmul_rn(wv.x, a23.y)));
    }
}

extern "C" void kernel_launch(void* const* d_in, const int* in_sizes, int n_in,
                              void* d_out, int out_size, void* d_ws, size_t ws_size,
                              hipStream_t stream) {
    const float* qxyz  = (const float*)d_in[0];
    const float* kxyz  = (const float*)d_in[1];
    const float* qfeat = (const float*)d_in[2];
    const float* kfeat = (const float*)d_in[3];
    float* out = (float*)d_out;

    float*  ws     = (float*)d_ws;
    float4* keys4  = (float4*)ws;                                // 65536 f
    int*    nn_idx = (int*)(ws + (size_t)4 * NB * N2);           // 262144 i
    float*  nn_w   = ws + (size_t)4 * NB * N2 + (size_t)4 * NB * N1;

    pack_keys<<<NB * (N2 / 256), 256, 0, stream>>>(kxyz, keys4);
    knn_scan<<<NB * (N1 / 256), 512, 0, stream>>>(qxyz, keys4, qfeat,
                                                  nn_idx, nn_w, out);
    interp8<<<NB * (C2 / CCH), 256, 0, stream>>>(kfeat, nn_idx, nn_w, out);
}